// Round 4
// baseline (1601.732 us; speedup 1.0000x reference)
//
#include <hip/hip_runtime.h>
#include <math.h>

#define T_MAXX 128
#define BATCHN 64
#define NC     32
#define BW     16
#define BLANKC 31
#define NEGF   (-1e30f)

typedef unsigned long long u64;
typedef unsigned int u32;

static const u64 PA_C = 0x100000001B3ULL;          // FNV prime
static const u64 PB_C = 6364136223846793005ULL;    // LCG multiplier

__device__ __forceinline__ float xexp(float x)  { return expf(x); }
__device__ __forceinline__ float xlog(float x)  { return logf(x); }
__device__ __forceinline__ float xlog1p(float x){ return log1pf(x); }

// jnp.logaddexp: max + log1p(exp(-|a-b|))
__device__ __forceinline__ float logaddexpf_(float a, float b) {
    float m = fmaxf(a, b);
    float d = fabsf(a - b);
    return m + xlog1p(xexp(-d));
}

// ---- DPP cross-lane helpers (VALU pipe, no LDS) ----
// invalid lanes keep old value (bound_ctrl=false) -> identity for max
template<int C>
__device__ __forceinline__ float fdpp_keep(float v) {
    return __int_as_float(__builtin_amdgcn_update_dpp(
        __float_as_int(v), __float_as_int(v), C, 0xF, 0xF, false));
}
// invalid lanes read 0 (bound_ctrl=true) -> identity for add
template<int C>
__device__ __forceinline__ float fdpp_zero(float v) {
    return __int_as_float(__builtin_amdgcn_update_dpp(
        0, __float_as_int(v), C, 0xF, 0xF, true));
}
template<int C>
__device__ __forceinline__ u32 udpp_keep(u32 v) {
    return (u32)__builtin_amdgcn_update_dpp((int)v, (int)v, C, 0xF, 0xF, false);
}

// full-wave (64-lane) reductions; result broadcast via readlane(63)
__device__ __forceinline__ float wave_fmax_bcast(float v) {
    v = fmaxf(v, fdpp_keep<0xB1>(v));    // quad_perm [1,0,3,2] : xor1
    v = fmaxf(v, fdpp_keep<0x4E>(v));    // quad_perm [2,3,0,1] : xor2
    v = fmaxf(v, fdpp_keep<0x141>(v));   // row_half_mirror     : other quad of 8
    v = fmaxf(v, fdpp_keep<0x140>(v));   // row_mirror          : other 8 of 16
    v = fmaxf(v, fdpp_keep<0x142>(v));   // row_bcast15
    v = fmaxf(v, fdpp_keep<0x143>(v));   // row_bcast31 -> lane63 = global
    return __int_as_float(__builtin_amdgcn_readlane(__float_as_int(v), 63));
}
__device__ __forceinline__ float wave_fsum_bcast(float v) {
    v += fdpp_zero<0xB1>(v);
    v += fdpp_zero<0x4E>(v);
    v += fdpp_zero<0x141>(v);
    v += fdpp_zero<0x140>(v);
    v += fdpp_zero<0x142>(v);
    v += fdpp_zero<0x143>(v);
    return __int_as_float(__builtin_amdgcn_readlane(__float_as_int(v), 63));
}
// 64-bit lexicographic max butterfly stage on (hi,lo) pair
template<int C>
__device__ __forceinline__ void pair_stage(u32 &mh, u32 &ml) {
    u32 oh = (u32)__builtin_amdgcn_update_dpp((int)mh, (int)mh, C, 0xF, 0xF, false);
    u32 ol = (u32)__builtin_amdgcn_update_dpp((int)ml, (int)ml, C, 0xF, 0xF, false);
    bool g = (oh > mh) || (oh == mh && ol > ml);
    mh = g ? oh : mh;
    ml = g ? ol : ml;
}

extern "C" __global__ void __launch_bounds__(64)
CTCPredictionsCpu_kernel(const float* __restrict__ data,
                         const int* __restrict__ dlen,
                         int* __restrict__ out)
{
    const int b      = blockIdx.x;
    const int tid    = threadIdx.x;
    const int length = dlen[b];
    const int lane_c = tid & 31;     // class owned by this lane
    const int lane_h = tid >> 5;     // row-half selector for ext rows

    __shared__ float logp[NC];
    __shared__ float ext[BW][NC];
    __shared__ float lpB[BW], lpNB[BW], lpTot[BW];
    __shared__ float stayBs[BW], stayNBs[BW], staySc[BW];
    __shared__ int   lens[BW], lastch[BW];
    __shared__ u64   hA[BW], hB[BW];
    __shared__ int   trace[T_MAXX][BW];   // src | char<<8 | is_ext<<16
    __shared__ int   outbuf[T_MAXX];

    if (tid < BW) {
        lens[tid]   = 0;
        lastch[tid] = -1;
        lpB[tid]    = (tid == 0) ? 0.0f : NEGF;
        lpNB[tid]   = NEGF;
        hA[tid]     = 1;
        hB[tid]     = 1;
    }
    __syncthreads();

    // pipelined frame load; all lanes load (lanes 32-63 duplicate classes)
    float xcur = (length > 0) ? data[(size_t)b * NC + lane_c] : 0.0f;

    for (int t = 0; t < length; ++t) {
        float xnext = (t + 1 < length)
                        ? data[((size_t)(t + 1) * BATCHN + b) * NC + lane_c] : 0.0f;

        // ---- log_softmax via DPP reductions (uniform shift: rankings invariant) ----
        float m = wave_fmax_bcast(xcur);                    // dup lanes harmless for max
        float e = (tid < NC) ? xexp(xcur - m) : 0.0f;       // dup lanes masked for sum
        float s = wave_fsum_bcast(e);
        float ls = xlog(s);
        float mylogp = (xcur - m) - ls;                     // logp of class lane_c
        if (tid < NC) logp[tid] = mylogp;
        float lpBlank = __int_as_float(
            __builtin_amdgcn_readlane(__float_as_int(mylogp), 31)); // class 31 = blank
        __syncthreads();                                    // B1

        // ---- stay candidates (lanes 0..15) ----
        if (tid < BW) {
            float a = lpB[tid], nb = lpNB[tid];
            float tot = logaddexpf_(a, nb);
            lpTot[tid]   = tot;
            stayBs[tid]  = tot + lpBlank;
            stayNBs[tid] = (lens[tid] > 0) ? (nb + logp[lastch[tid]]) : NEGF;
        }
        __syncthreads();                                    // B2

        // ---- ext[i][c]: lane owns col c=lane_c, rows i = 2*s + lane_h ----
        #pragma unroll
        for (int s8 = 0; s8 < 8; ++s8) {
            int i = 2 * s8 + lane_h;
            float base = (lane_c == lastch[i]) ? lpB[i] : lpTot[i];
            float v = base + mylogp;
            if (lane_c == BLANKC) v = NEGF;
            ext[i][lane_c] = v;
        }
        __syncthreads();                                    // B3

        // ---- merge ext(i,c) into stay(j): 4 lanes per beam j, quad-DPP combine ----
        {
            const int j = tid >> 2, g = tid & 3;
            const int   lj  = lens[j];
            const int   cj  = lastch[j];
            const bool  valid = lpTot[j] > -5e29f;
            const u64   tAj = hA[j], tBj = hB[j];
            const u64   addv = (u64)(cj + 1);
            u32   mmask = 0;
            float mm = NEGF;
            if (valid && lj > 0) {
                #pragma unroll
                for (int q = 0; q < 4; ++q) {
                    int i = 4 * g + q;
                    if (lens[i] + 1 == lj &&
                        tAj == hA[i] * PA_C + addv &&
                        tBj == hB[i] * PB_C + addv) {
                        mm = fmaxf(mm, ext[i][cj]);
                        mmask |= 1u << i;
                    }
                }
            }
            mm = fmaxf(mm, fdpp_keep<0xB1>(mm));            // quad max
            mm = fmaxf(mm, fdpp_keep<0x4E>(mm));
            float ssum = 0.0f;
            if (mmask) {
                #pragma unroll
                for (int q = 0; q < 4; ++q) {
                    int i = 4 * g + q;
                    if (mmask & (1u << i)) ssum += xexp(ext[i][cj] - mm);
                }
            }
            ssum += fdpp_zero<0xB1>(ssum);                  // quad sum
            ssum += fdpp_zero<0x4E>(ssum);
            u32 allmask = mmask;
            allmask |= udpp_keep<0xB1>(allmask);
            allmask |= udpp_keep<0x4E>(allmask);
            if (g == 0) {
                float merged = allmask ? (mm + xlog(ssum)) : NEGF;
                float snb = logaddexpf_(stayNBs[j], merged);
                stayNBs[j] = snb;
                staySc[j]  = logaddexpf_(stayBs[j], snb);
            }
            // mask consumed entries in-place (all reads above precede these writes
            // in single-wave program order; (i,cj) targets are collision-free)
            if (mmask) {
                #pragma unroll
                for (int q = 0; q < 4; ++q) {
                    int i = 4 * g + q;
                    if (mmask & (1u << i)) ext[i][cj] = NEGF;
                }
            }
        }
        __syncthreads();                                    // B4

        // ---- build 9 keys/lane: slot0 = stay(tid), slots 1..8 = ext rows ----
        u32 kh[9], kl[9];
        {
            float sc = (tid < BW) ? staySc[tid] : NEGF;
            u32 u = __float_as_uint(sc);
            u = (u & 0x80000000u) ? ~u : (u | 0x80000000u);
            kh[0] = (tid < BW) ? u : 0u;
            kl[0] = (tid < BW) ? (0xFFFFFFFFu - (u32)tid) : 0u;
            #pragma unroll
            for (int s8 = 0; s8 < 8; ++s8) {
                int i = 2 * s8 + lane_h;
                u32 uu = __float_as_uint(ext[i][lane_c]);
                uu = (uu & 0x80000000u) ? ~uu : (uu | 0x80000000u);
                kh[s8 + 1] = uu;
                kl[s8 + 1] = 0xFFFFFFFFu - (u32)(BW + i * NC + lane_c);
            }
        }

        // ---- top-16: 16 rounds of DPP argmax over (value, ~idx) pairs ----
        int myidx = 0;
        #pragma unroll 1
        for (int k = 0; k < BW; ++k) {
            u32 mh = kh[0], ml = kl[0];
            #pragma unroll
            for (int r = 1; r < 9; ++r) {
                bool g = (kh[r] > mh) || (kh[r] == mh && kl[r] > ml);
                mh = g ? kh[r] : mh;
                ml = g ? kl[r] : ml;
            }
            pair_stage<0xB1>(mh, ml);
            pair_stage<0x4E>(mh, ml);
            pair_stage<0x141>(mh, ml);
            pair_stage<0x140>(mh, ml);
            pair_stage<0x142>(mh, ml);
            pair_stage<0x143>(mh, ml);
            u32 bh = (u32)__builtin_amdgcn_readlane((int)mh, 63);
            u32 bl = (u32)__builtin_amdgcn_readlane((int)ml, 63);
            if (tid == k) myidx = (int)(0xFFFFFFFFu - bl);
            #pragma unroll
            for (int r = 0; r < 9; ++r)
                if (kh[r] == bh && kl[r] == bl) { kh[r] = 0; kl[r] = 0; }
        }

        // ---- state update (reads precede writes in single-wave program order) ----
        int nlen = 0, nlast = 0, trc = 0;
        float nb_ = 0.0f, nnb_ = 0.0f;
        u64 nA = 0, nB = 0;
        if (tid < BW) {
            int idx = myidx;
            bool isext = idx >= BW;
            int istay = isext ? 0 : idx;
            int e2 = isext ? (idx - BW) : 0;
            int ie = e2 >> 5, ce = e2 & 31;
            int src = isext ? ie : istay;
            nlen  = lens[src] + (isext ? 1 : 0);
            nb_   = isext ? NEGF : stayBs[istay];
            nnb_  = isext ? ext[ie][ce] : stayNBs[istay];
            nlast = isext ? ce : lastch[src];
            nA    = isext ? (hA[src] * PA_C + (u64)(ce + 1)) : hA[src];
            nB    = isext ? (hB[src] * PB_C + (u64)(ce + 1)) : hB[src];
            trc   = src | (ce << 8) | (isext ? (1 << 16) : 0);
        }
        if (tid < BW) {
            lens[tid] = nlen;  lastch[tid] = nlast;
            lpB[tid]  = nb_;   lpNB[tid]   = nnb_;
            hA[tid]   = nA;    hB[tid]     = nB;
            trace[t][tid] = trc;
        }
        xcur = xnext;
        // no barrier needed: next iteration's cross-lane state reads occur after B1
    }

    // ---- backtrack beam 0 to dense output (padded with BLANK_PAD = 0) ----
    for (int l = tid; l < T_MAXX; l += 64) outbuf[l] = 0;
    __syncthreads();
    if (tid == 0) {
        int cur = 0;
        int pos = lens[0] - 1;
        for (int s = length - 1; s >= 0; --s) {
            int e = trace[s][cur];
            if (e & (1 << 16)) outbuf[pos--] = (e >> 8) & 0xFF;
            cur = e & 0xFF;
        }
    }
    __syncthreads();
    for (int l = tid; l < T_MAXX; l += 64) out[b * T_MAXX + l] = outbuf[l];
}

extern "C" void kernel_launch(void* const* d_in, const int* in_sizes, int n_in,
                              void* d_out, int out_size, void* d_ws, size_t ws_size,
                              hipStream_t stream) {
    const float* data = (const float*)d_in[0];
    const int*   dlen = (const int*)d_in[1];
    int*         out  = (int*)d_out;
    hipLaunchKernelGGL(CTCPredictionsCpu_kernel, dim3(BATCHN), dim3(64), 0, stream,
                       data, dlen, out);
}

// Round 5
// 758.401 us; speedup vs baseline: 2.1120x; 2.1120x over previous
//
#include <hip/hip_runtime.h>
#include <math.h>

#define T_MAXX 128
#define BATCHN 64
#define NC     32
#define BW     16
#define BLANKC 31
#define NEGF   (-1e30f)

typedef unsigned long long u64;
typedef unsigned int u32;

static const u64 PA_C = 0x100000001B3ULL;          // FNV prime
static const u64 PB_C = 6364136223846793005ULL;    // LCG multiplier

// single-wave block: hardware executes a wave's LDS ops in order; we only
// need to stop the COMPILER from reordering LDS accesses across phases.
#define FENCE() asm volatile("" ::: "memory")

__device__ __forceinline__ float xexp(float x)  { return expf(x); }
__device__ __forceinline__ float xlog(float x)  { return logf(x); }
__device__ __forceinline__ float xlog1p(float x){ return log1pf(x); }

// jnp.logaddexp: max + log1p(exp(-|a-b|))
__device__ __forceinline__ float logaddexpf_(float a, float b) {
    float m = fmaxf(a, b);
    float d = fabsf(a - b);
    return m + xlog1p(xexp(-d));
}

// ---- DPP cross-lane helpers (VALU pipe) ----
template<int C>
__device__ __forceinline__ float fdpp_keep(float v) {
    return __int_as_float(__builtin_amdgcn_update_dpp(
        __float_as_int(v), __float_as_int(v), C, 0xF, 0xF, false));
}
template<int C>
__device__ __forceinline__ float fdpp_zero(float v) {
    return __int_as_float(__builtin_amdgcn_update_dpp(
        0, __float_as_int(v), C, 0xF, 0xF, true));
}
template<int C>
__device__ __forceinline__ u32 udpp_keep(u32 v) {
    return (u32)__builtin_amdgcn_update_dpp((int)v, (int)v, C, 0xF, 0xF, false);
}
template<int C>
__device__ __forceinline__ u64 dpp64_keep(u64 v) {
    u32 lo = udpp_keep<C>((u32)v);
    u32 hi = udpp_keep<C>((u32)(v >> 32));
    return ((u64)hi << 32) | lo;
}

__device__ __forceinline__ float wave_fmax_bcast(float v) {
    v = fmaxf(v, fdpp_keep<0xB1>(v));
    v = fmaxf(v, fdpp_keep<0x4E>(v));
    v = fmaxf(v, fdpp_keep<0x141>(v));
    v = fmaxf(v, fdpp_keep<0x140>(v));
    v = fmaxf(v, fdpp_keep<0x142>(v));
    v = fmaxf(v, fdpp_keep<0x143>(v));
    return __int_as_float(__builtin_amdgcn_readlane(__float_as_int(v), 63));
}
__device__ __forceinline__ float wave_fsum_bcast(float v) {
    v += fdpp_zero<0xB1>(v);
    v += fdpp_zero<0x4E>(v);
    v += fdpp_zero<0x141>(v);
    v += fdpp_zero<0x140>(v);
    v += fdpp_zero<0x142>(v);
    v += fdpp_zero<0x143>(v);
    return __int_as_float(__builtin_amdgcn_readlane(__float_as_int(v), 63));
}
// full-wave u64 max, result broadcast (distinct keys -> unique winner)
__device__ __forceinline__ u64 wave_umax64_bcast(u64 m) {
    { u64 o = dpp64_keep<0xB1>(m);  if (o > m) m = o; }
    { u64 o = dpp64_keep<0x4E>(m);  if (o > m) m = o; }
    { u64 o = dpp64_keep<0x141>(m); if (o > m) m = o; }
    { u64 o = dpp64_keep<0x140>(m); if (o > m) m = o; }
    { u64 o = dpp64_keep<0x142>(m); if (o > m) m = o; }
    { u64 o = dpp64_keep<0x143>(m); if (o > m) m = o; }
    u32 hi = (u32)__builtin_amdgcn_readlane((int)(u32)(m >> 32), 63);
    u32 lo = (u32)__builtin_amdgcn_readlane((int)(u32)m, 63);
    return ((u64)hi << 32) | lo;
}

extern "C" __global__ void __launch_bounds__(64)
CTCPredictionsCpu_kernel(const float* __restrict__ data,
                         const int* __restrict__ dlen,
                         int* __restrict__ out)
{
    const int b      = blockIdx.x;
    const int tid    = threadIdx.x;
    const int length = dlen[b];
    const int lane_c = tid & 31;
    const int lane_h = tid >> 5;

    __shared__ float ext[BW][NC];
    __shared__ int   lensS[BW], lastS[BW];
    __shared__ float lpBS[BW], lpTotS[BW];
    __shared__ u64   hAS[BW], hBS[BW];     // raw hashes
    __shared__ u64   hAXS[BW], hBXS[BW];   // pre-multiplied: h * P
    __shared__ int   trace[T_MAXX][BW];    // src | char<<8 | is_ext<<16
    __shared__ int   outbuf[T_MAXX];

    // beam state in registers of lanes 0..15 (lane j owns beam j)
    int   myLen  = 0;
    int   myLast = -1;
    float myLpB  = (tid == 0) ? 0.0f : NEGF;
    float myLpNB = NEGF;
    u64   myHA   = 1, myHB = 1;

    float xcur = data[(size_t)b * NC + lane_c];   // length >= 1 always

    for (int t = 0; t < length; ++t) {
        // prefetch next frame; with no barriers the vmcnt wait lands at the
        // loop-bottom use, hidden under the whole step's compute
        float xnext = (t + 1 < length)
                        ? data[((size_t)(t + 1) * BATCHN + b) * NC + lane_c] : 0.0f;

        // ---- log_softmax via DPP (uniform shift: rankings invariant) ----
        float m = wave_fmax_bcast(xcur);
        float e = (tid < NC) ? xexp(xcur - m) : 0.0f;
        float s = wave_fsum_bcast(e);
        float ls = xlog(s);
        float mylogp = (xcur - m) - ls;
        float lpBlank = __int_as_float(
            __builtin_amdgcn_readlane(__float_as_int(mylogp), 31));

        // ---- stay candidates (registers) + publish state to LDS ----
        float lp_last = __shfl(mylogp, (myLast >= 0) ? myLast : 0, 32);
        float myTot = 0.0f, stayB = 0.0f, stayNB = 0.0f;
        if (tid < BW) {
            myTot  = logaddexpf_(myLpB, myLpNB);
            stayB  = myTot + lpBlank;
            stayNB = (myLen > 0) ? (myLpNB + lp_last) : NEGF;
            lensS[tid]  = myLen;
            lastS[tid]  = myLast;
            lpBS[tid]   = myLpB;
            lpTotS[tid] = myTot;
            hAS[tid]    = myHA;
            hBS[tid]    = myHB;
            hAXS[tid]   = myHA * PA_C;
            hBXS[tid]   = myHB * PB_C;
        }
        FENCE();

        // ---- ext[i][c]: lane owns col lane_c, rows i = 2*s8 + lane_h ----
        #pragma unroll
        for (int s8 = 0; s8 < 8; ++s8) {
            int i = 2 * s8 + lane_h;
            float base = (lane_c == lastS[i]) ? lpBS[i] : lpTotS[i];
            float v = base + mylogp;
            if (lane_c == BLANKC) v = NEGF;
            ext[i][lane_c] = v;
        }
        FENCE();

        // ---- merge ext(i,c) into stay(j): lane j serial over i (reads batch) ----
        float staySc = NEGF;
        if (tid < BW) {
            bool valid = myTot > -5e29f;
            if (valid && myLen > 0) {
                const int cj = myLast;
                const int ljm1 = myLen - 1;
                const u64 wantA = myHA - (u64)(cj + 1);  // hAXS[i] == wantA
                const u64 wantB = myHB - (u64)(cj + 1);
                float mm = NEGF; u32 mmask = 0;
                #pragma unroll
                for (int i = 0; i < BW; ++i) {
                    if (lensS[i] == ljm1 && hAXS[i] == wantA && hBXS[i] == wantB) {
                        mm = fmaxf(mm, ext[i][cj]);
                        mmask |= 1u << i;
                    }
                }
                if (mmask) {
                    float ssum = 0.0f;
                    #pragma unroll
                    for (int i = 0; i < BW; ++i) {
                        if (mmask & (1u << i)) {
                            ssum += xexp(ext[i][cj] - mm);
                            ext[i][cj] = NEGF;          // consume (disjoint cells)
                        }
                    }
                    float merged = mm + xlog(ssum);
                    stayNB = logaddexpf_(stayNB, merged);
                }
            }
            staySc = logaddexpf_(stayB, stayNB);
        }
        FENCE();

        // ---- keys: slot0 = stay(tid), slots 1..8 = this lane's ext cells ----
        u64 K[9];
        {
            u32 u = __float_as_uint(staySc);
            u = (u & 0x80000000u) ? ~u : (u | 0x80000000u);
            K[0] = (tid < BW) ? (((u64)u << 32) | (u64)(0xFFFFFFFFu - (u32)tid))
                              : 0ULL;
            #pragma unroll
            for (int s8 = 0; s8 < 8; ++s8) {
                int i = 2 * s8 + lane_h;
                u32 uu = __float_as_uint(ext[i][lane_c]);   // post-merge value
                uu = (uu & 0x80000000u) ? ~uu : (uu | 0x80000000u);
                K[s8 + 1] = ((u64)uu << 32)
                          | (u64)(0xFFFFFFFFu - (u32)(BW + i * NC + lane_c));
            }
        }

        // ---- per-lane sort 9 desc: Batcher-8 + insertion of K[8] ----
        #define CE(a,bb) { if (K[bb] > K[a]) { u64 t_ = K[a]; K[a] = K[bb]; K[bb] = t_; } }
        CE(0,1) CE(2,3) CE(4,5) CE(6,7)
        CE(0,2) CE(1,3) CE(4,6) CE(5,7)
        CE(1,2) CE(5,6)
        CE(0,4) CE(1,5) CE(2,6) CE(3,7)
        CE(2,4) CE(3,5)
        CE(1,2) CE(3,4) CE(5,6)
        CE(7,8) CE(6,7) CE(5,6) CE(4,5) CE(3,4) CE(2,3) CE(1,2) CE(0,1)
        #undef CE

        // ---- tournament: 16 rounds of head-max + winner shift-down ----
        int myidx = 0;
        #pragma unroll
        for (int k = 0; k < BW; ++k) {
            u64 best = wave_umax64_bcast(K[0]);
            if (tid == k) myidx = (int)(0xFFFFFFFFu - (u32)best);
            bool win = (K[0] == best);
            #pragma unroll
            for (int r = 0; r < 8; ++r) K[r] = win ? K[r + 1] : K[r];
            K[8] = win ? 0ULL : K[8];
        }

        // ---- state update ----
        bool isext = (tid < BW) && (myidx >= BW);
        int  istay = (tid < BW && !isext) ? myidx : 0;
        float gB  = __shfl(stayB,  istay, 32);
        float gNB = __shfl(stayNB, istay, 32);
        if (tid < BW) {
            int e2 = isext ? (myidx - BW) : 0;
            int ie = e2 >> 5, ce = e2 & 31;
            int src = isext ? ie : istay;
            int  sLen  = lensS[src];
            int  sLast = lastS[src];
            u64  sHA   = hAS[src], sHB = hBS[src];
            u64  sHAX  = hAXS[src], sHBX = hBXS[src];
            float extv = ext[ie][ce];
            myLen  = sLen + (isext ? 1 : 0);
            myLast = isext ? ce : sLast;
            myLpB  = isext ? NEGF : gB;
            myLpNB = isext ? extv : gNB;
            myHA   = isext ? (sHAX + (u64)(ce + 1)) : sHA;
            myHB   = isext ? (sHBX + (u64)(ce + 1)) : sHB;
            trace[t][tid] = src | (ce << 8) | (isext ? (1 << 16) : 0);
        }
        FENCE();

        xcur = xnext;
    }

    // ---- backtrack beam 0 (lane 0 holds its length) ----
    FENCE();
    for (int l = tid; l < T_MAXX; l += 64) outbuf[l] = 0;
    FENCE();
    if (tid == 0) {
        int cur = 0;
        int pos = myLen - 1;
        for (int s = length - 1; s >= 0; --s) {
            int e = trace[s][cur];
            if (e & (1 << 16)) outbuf[pos--] = (e >> 8) & 0xFF;
            cur = e & 0xFF;
        }
    }
    FENCE();
    for (int l = tid; l < T_MAXX; l += 64) out[b * T_MAXX + l] = outbuf[l];
}

extern "C" void kernel_launch(void* const* d_in, const int* in_sizes, int n_in,
                              void* d_out, int out_size, void* d_ws, size_t ws_size,
                              hipStream_t stream) {
    const float* data = (const float*)d_in[0];
    const int*   dlen = (const int*)d_in[1];
    int*         out  = (int*)d_out;
    hipLaunchKernelGGL(CTCPredictionsCpu_kernel, dim3(BATCHN), dim3(64), 0, stream,
                       data, dlen, out);
}